// Round 2
// baseline (340.744 us; speedup 1.0000x reference)
//
#include <hip/hip_runtime.h>
#include <math.h>

#define TT 2048
#define NN 8192
#define HH 128
#define TPB 4   // timesteps per mlp block

typedef float f4 __attribute__((ext_vector_type(4)));

// ---------------------------------------------------------------------------
// Stage 1: per-timestep MLP -> A, stored TRANSPOSED: A_t[e*TT + t], e in [0,16)
// 4 timesteps per 128-thread block: W2/W3 loads amortized 4x.
// ---------------------------------------------------------------------------
__global__ __launch_bounds__(HH) void mlp_kernel(
        const float* __restrict__ t_arr, const float* __restrict__ M0,
        const float* __restrict__ W1, const float* __restrict__ b1,
        const float* __restrict__ W2, const float* __restrict__ b2,
        const float* __restrict__ W3, const float* __restrict__ b3,
        float* __restrict__ A_t) {
    const int tb = blockIdx.x * TPB;
    const int j = threadIdx.x;
    __shared__ float h1[TPB][HH];
    __shared__ float h2[TPB][HH];
    __shared__ float dts[TPB];

    #pragma unroll
    for (int q = 0; q < TPB; ++q) {
        const int t = tb + q;
        const float t_cur  = t_arr[t];
        const float t_prev = (t > 0) ? t_arr[t - 1] : 0.0f;
        if (j == 0) dts[q] = t_cur - t_prev;
        const float ta = 0.5f * (t_cur + t_prev);
        h1[q][j] = tanhf(fmaf(ta, W1[j], b1[j]));
    }
    __syncthreads();

    float acc[TPB];
    #pragma unroll
    for (int q = 0; q < TPB; ++q) acc[q] = b2[j];
    #pragma unroll 4
    for (int i = 0; i < HH; ++i) {
        const float w = W2[i * HH + j];          // coalesced over j
        #pragma unroll
        for (int q = 0; q < TPB; ++q) acc[q] = fmaf(h1[q][i], w, acc[q]);
    }
    #pragma unroll
    for (int q = 0; q < TPB; ++q) h2[q][j] = tanhf(acc[q]);
    __syncthreads();

    if (j < 16) {
        float a[TPB];
        #pragma unroll
        for (int q = 0; q < TPB; ++q) a[q] = b3[j];
        #pragma unroll 4
        for (int i = 0; i < HH; ++i) {
            const float w = W3[i * 16 + j];
            #pragma unroll
            for (int q = 0; q < TPB; ++q) a[q] = fmaf(h2[q][i], w, a[q]);
        }
        #pragma unroll
        for (int q = 0; q < TPB; ++q)
            A_t[j * TT + tb + q] = (a[q] + M0[j]) * dts[q];
    }
}

// ---------------------------------------------------------------------------
// Stage 2+3 fused: cumsum over t (16 sequences) then batched 4x4 expm.
// Single block, 1024 threads. Asum round-trips through global ws; same-block
// RAW is __syncthreads-visible (same CU/L1).
// ---------------------------------------------------------------------------
__device__ __forceinline__ void mm4(const float* __restrict__ A,
                                    const float* __restrict__ B,
                                    float* __restrict__ C) {
    #pragma unroll
    for (int i = 0; i < 4; ++i)
        #pragma unroll
        for (int j = 0; j < 4; ++j) {
            float s = 0.0f;
            #pragma unroll
            for (int k = 0; k < 4; ++k) s = fmaf(A[i * 4 + k], B[k * 4 + j], s);
            C[i * 4 + j] = s;
        }
}

__global__ __launch_bounds__(1024) void scan_expm_kernel(
        const float* __restrict__ A_t, float* __restrict__ Asum,
        float* __restrict__ E) {
    const int tid = threadIdx.x;
    const int e = tid >> 6;        // 0..15
    const int c = tid & 63;        // 0..63
    const float* src = A_t + e * TT + c * 32;

    float v[32];
    float s = 0.0f;
    #pragma unroll
    for (int i = 0; i < 32; ++i) { v[i] = src[i]; s += v[i]; }

    __shared__ float cs[16 * 64];
    cs[e * 64 + c] = s;
    __syncthreads();

    if (c == 0) {  // 16 serial leaders: exclusive scan of 64 chunk sums
        float run = 0.0f;
        const int base = e * 64;
        for (int i = 0; i < 64; ++i) {
            const float xv = cs[base + i];
            cs[base + i] = run;
            run += xv;
        }
    }
    __syncthreads();

    float run = cs[e * 64 + c];
    const int t0 = c * 32;
    #pragma unroll
    for (int i = 0; i < 32; ++i) {
        run += v[i];
        Asum[(t0 + i) * 16 + e] = run;
    }
    __threadfence_block();
    __syncthreads();

    // --- expm: each thread handles t = tid and t + 1024 ---
    for (int t = tid; t < TT; t += 1024) {
        float M[16];
        const f4* ms = (const f4*)(Asum + t * 16);
        #pragma unroll
        for (int r = 0; r < 4; ++r) {
            f4 vv = ms[r];
            M[r*4+0] = vv.x; M[r*4+1] = vv.y; M[r*4+2] = vv.z; M[r*4+3] = vv.w;
        }
        float nrm = 0.0f;
        #pragma unroll
        for (int i = 0; i < 4; ++i) {
            float rs = fabsf(M[i*4+0]) + fabsf(M[i*4+1]) + fabsf(M[i*4+2]) + fabsf(M[i*4+3]);
            nrm = fmaxf(nrm, rs);
        }
        int k = 0;
        while (nrm > 0.5f && k < 40) { nrm *= 0.5f; ++k; }
        const float sc = ldexpf(1.0f, -k);
        #pragma unroll
        for (int i = 0; i < 16; ++i) M[i] *= sc;

        float R[16], P[16], Q[16];
        #pragma unroll
        for (int i = 0; i < 16; ++i) { P[i] = M[i]; R[i] = M[i]; }
        R[0] += 1.0f; R[5] += 1.0f; R[10] += 1.0f; R[15] += 1.0f;
        for (int n = 2; n <= 12; ++n) {
            mm4(P, M, Q);
            const float inv = 1.0f / (float)n;
            #pragma unroll
            for (int i = 0; i < 16; ++i) { P[i] = Q[i] * inv; R[i] += P[i]; }
        }
        for (int sq = 0; sq < k; ++sq) {
            mm4(R, R, Q);
            #pragma unroll
            for (int i = 0; i < 16; ++i) R[i] = Q[i];
        }
        f4* dst = (f4*)(E + t * 16);
        #pragma unroll
        for (int r = 0; r < 4; ++r) {
            f4 o; o.x = R[r*4+0]; o.y = R[r*4+1]; o.z = R[r*4+2]; o.w = R[r*4+3];
            dst[r] = o;
        }
    }
}

// ---------------------------------------------------------------------------
// Stage 4: out[t,n,:] = E[t] @ x[n].  256 MB write-bound epilogue.
// grid (NN/1024, TT), 256 threads, 4 float4 stores per thread (nontemporal).
// E read via wave-uniform scalar loads (t = blockIdx.y) — no LDS, no barrier.
// ---------------------------------------------------------------------------
__global__ __launch_bounds__(256) void apply_kernel(
        const float* __restrict__ E, const float* __restrict__ x,
        float* __restrict__ out) {
    const int t = blockIdx.y;
    const float* __restrict__ Ep = E + t * 16;
    const float e0 = Ep[0],  e1 = Ep[1],  e2 = Ep[2],  e3 = Ep[3];
    const float e4 = Ep[4],  e5 = Ep[5],  e6 = Ep[6],  e7 = Ep[7];
    const float e8 = Ep[8],  e9 = Ep[9],  e10 = Ep[10], e11 = Ep[11];
    const float e12 = Ep[12], e13 = Ep[13], e14 = Ep[14], e15 = Ep[15];

    const f4* __restrict__ x4 = (const f4*)x;
    f4* __restrict__ o4 = (f4*)out + (size_t)t * NN;
    const int base = blockIdx.x * 1024 + threadIdx.x;

    #pragma unroll
    for (int k = 0; k < 4; ++k) {
        const int n = base + k * 256;
        const f4 xv = x4[n];
        f4 o;
        o.x = fmaf(e0,  xv.x, fmaf(e1,  xv.y, fmaf(e2,  xv.z, e3  * xv.w)));
        o.y = fmaf(e4,  xv.x, fmaf(e5,  xv.y, fmaf(e6,  xv.z, e7  * xv.w)));
        o.z = fmaf(e8,  xv.x, fmaf(e9,  xv.y, fmaf(e10, xv.z, e11 * xv.w)));
        o.w = fmaf(e12, xv.x, fmaf(e13, xv.y, fmaf(e14, xv.z, e15 * xv.w)));
        __builtin_nontemporal_store(o, &o4[n]);
    }
}

// ---------------------------------------------------------------------------
extern "C" void kernel_launch(void* const* d_in, const int* in_sizes, int n_in,
                              void* d_out, int out_size, void* d_ws, size_t ws_size,
                              hipStream_t stream) {
    const float* x  = (const float*)d_in[0];
    const float* t  = (const float*)d_in[1];
    const float* M0 = (const float*)d_in[2];
    const float* W1 = (const float*)d_in[3];
    const float* b1 = (const float*)d_in[4];
    const float* W2 = (const float*)d_in[5];
    const float* b2 = (const float*)d_in[6];
    const float* W3 = (const float*)d_in[7];
    const float* b3 = (const float*)d_in[8];
    float* out = (float*)d_out;

    float* A_t  = (float*)d_ws;           // 16*TT floats (transposed)
    float* Asum = A_t  + 16 * TT;         // 16*TT floats (t-major)
    float* E    = Asum + 16 * TT;         // 16*TT floats (t-major)

    mlp_kernel<<<TT / TPB, HH, 0, stream>>>(t, M0, W1, b1, W2, b2, W3, b3, A_t);
    scan_expm_kernel<<<1, 1024, 0, stream>>>(A_t, Asum, E);
    apply_kernel<<<dim3(NN / 1024, TT), 256, 0, stream>>>(E, x, out);
}

// Round 3
// 334.383 us; speedup vs baseline: 1.0190x; 1.0190x over previous
//
#include <hip/hip_runtime.h>
#include <math.h>

#define TT 2048
#define NN 8192
#define HH 128
#define TPB 4   // timesteps per mlp block

typedef float f4 __attribute__((ext_vector_type(4)));

// ---------------------------------------------------------------------------
// Stage 1: per-timestep MLP -> A, stored TRANSPOSED: A_t[e*TT + t], e in [0,16)
// 4 timesteps per 128-thread block: W2/W3 loads amortized 4x.
// ---------------------------------------------------------------------------
__global__ __launch_bounds__(HH) void mlp_kernel(
        const float* __restrict__ t_arr, const float* __restrict__ M0,
        const float* __restrict__ W1, const float* __restrict__ b1,
        const float* __restrict__ W2, const float* __restrict__ b2,
        const float* __restrict__ W3, const float* __restrict__ b3,
        float* __restrict__ A_t) {
    const int tb = blockIdx.x * TPB;
    const int j = threadIdx.x;
    __shared__ float h1[TPB][HH];
    __shared__ float h2[TPB][HH];
    __shared__ float dts[TPB];

    #pragma unroll
    for (int q = 0; q < TPB; ++q) {
        const int t = tb + q;
        const float t_cur  = t_arr[t];
        const float t_prev = (t > 0) ? t_arr[t - 1] : 0.0f;
        if (j == 0) dts[q] = t_cur - t_prev;
        const float ta = 0.5f * (t_cur + t_prev);
        h1[q][j] = tanhf(fmaf(ta, W1[j], b1[j]));
    }
    __syncthreads();

    float acc[TPB];
    #pragma unroll
    for (int q = 0; q < TPB; ++q) acc[q] = b2[j];
    #pragma unroll 4
    for (int i = 0; i < HH; ++i) {
        const float w = W2[i * HH + j];          // coalesced over j
        #pragma unroll
        for (int q = 0; q < TPB; ++q) acc[q] = fmaf(h1[q][i], w, acc[q]);
    }
    #pragma unroll
    for (int q = 0; q < TPB; ++q) h2[q][j] = tanhf(acc[q]);
    __syncthreads();

    if (j < 16) {
        float a[TPB];
        #pragma unroll
        for (int q = 0; q < TPB; ++q) a[q] = b3[j];
        #pragma unroll 4
        for (int i = 0; i < HH; ++i) {
            const float w = W3[i * 16 + j];
            #pragma unroll
            for (int q = 0; q < TPB; ++q) a[q] = fmaf(h2[q][i], w, a[q]);
        }
        #pragma unroll
        for (int q = 0; q < TPB; ++q)
            A_t[j * TT + tb + q] = (a[q] + M0[j]) * dts[q];
    }
}

// ---------------------------------------------------------------------------
// Stage 2+3 fused: cumsum over t (16 sequences) then batched 4x4 expm.
// Single block, 1024 threads. Asum round-trips through global ws; same-block
// RAW is __syncthreads-visible (same CU/L1).
// ---------------------------------------------------------------------------
__device__ __forceinline__ void mm4(const float* __restrict__ A,
                                    const float* __restrict__ B,
                                    float* __restrict__ C) {
    #pragma unroll
    for (int i = 0; i < 4; ++i)
        #pragma unroll
        for (int j = 0; j < 4; ++j) {
            float s = 0.0f;
            #pragma unroll
            for (int k = 0; k < 4; ++k) s = fmaf(A[i * 4 + k], B[k * 4 + j], s);
            C[i * 4 + j] = s;
        }
}

__global__ __launch_bounds__(1024) void scan_expm_kernel(
        const float* __restrict__ A_t, float* __restrict__ Asum,
        float* __restrict__ E) {
    const int tid = threadIdx.x;
    const int e = tid >> 6;        // 0..15
    const int c = tid & 63;        // 0..63
    const float* src = A_t + e * TT + c * 32;

    float v[32];
    float s = 0.0f;
    #pragma unroll
    for (int i = 0; i < 32; ++i) { v[i] = src[i]; s += v[i]; }

    __shared__ float cs[16 * 64];
    cs[e * 64 + c] = s;
    __syncthreads();

    if (c == 0) {  // 16 serial leaders: exclusive scan of 64 chunk sums
        float run = 0.0f;
        const int base = e * 64;
        for (int i = 0; i < 64; ++i) {
            const float xv = cs[base + i];
            cs[base + i] = run;
            run += xv;
        }
    }
    __syncthreads();

    float run = cs[e * 64 + c];
    const int t0 = c * 32;
    #pragma unroll
    for (int i = 0; i < 32; ++i) {
        run += v[i];
        Asum[(t0 + i) * 16 + e] = run;
    }
    __threadfence_block();
    __syncthreads();

    // --- expm: each thread handles t = tid and t + 1024 ---
    for (int t = tid; t < TT; t += 1024) {
        float M[16];
        const f4* ms = (const f4*)(Asum + t * 16);
        #pragma unroll
        for (int r = 0; r < 4; ++r) {
            f4 vv = ms[r];
            M[r*4+0] = vv.x; M[r*4+1] = vv.y; M[r*4+2] = vv.z; M[r*4+3] = vv.w;
        }
        float nrm = 0.0f;
        #pragma unroll
        for (int i = 0; i < 4; ++i) {
            float rs = fabsf(M[i*4+0]) + fabsf(M[i*4+1]) + fabsf(M[i*4+2]) + fabsf(M[i*4+3]);
            nrm = fmaxf(nrm, rs);
        }
        int k = 0;
        while (nrm > 0.5f && k < 40) { nrm *= 0.5f; ++k; }
        const float sc = ldexpf(1.0f, -k);
        #pragma unroll
        for (int i = 0; i < 16; ++i) M[i] *= sc;

        float R[16], P[16], Q[16];
        #pragma unroll
        for (int i = 0; i < 16; ++i) { P[i] = M[i]; R[i] = M[i]; }
        R[0] += 1.0f; R[5] += 1.0f; R[10] += 1.0f; R[15] += 1.0f;
        for (int n = 2; n <= 12; ++n) {
            mm4(P, M, Q);
            const float inv = 1.0f / (float)n;
            #pragma unroll
            for (int i = 0; i < 16; ++i) { P[i] = Q[i] * inv; R[i] += P[i]; }
        }
        for (int sq = 0; sq < k; ++sq) {
            mm4(R, R, Q);
            #pragma unroll
            for (int i = 0; i < 16; ++i) R[i] = Q[i];
        }
        f4* dst = (f4*)(E + t * 16);
        #pragma unroll
        for (int r = 0; r < 4; ++r) {
            f4 o; o.x = R[r*4+0]; o.y = R[r*4+1]; o.z = R[r*4+2]; o.w = R[r*4+3];
            dst[r] = o;
        }
    }
}

// ---------------------------------------------------------------------------
// Stage 4: out[t,n,:] = E[t] @ x[n].  256 MB write-bound epilogue.
// grid (NN/1024, TT), 256 threads, 4 float4 stores per thread.
// PLAIN cached stores — R2's nontemporal stores are the suspected -35 µs
// regression (write stream lost L2 write-combining/scheduling).
// E read via wave-uniform scalar loads (t = blockIdx.y) — no LDS, no barrier.
// ---------------------------------------------------------------------------
__global__ __launch_bounds__(256) void apply_kernel(
        const float* __restrict__ E, const float* __restrict__ x,
        float* __restrict__ out) {
    const int t = blockIdx.y;
    const float* __restrict__ Ep = E + t * 16;
    const float e0 = Ep[0],  e1 = Ep[1],  e2 = Ep[2],  e3 = Ep[3];
    const float e4 = Ep[4],  e5 = Ep[5],  e6 = Ep[6],  e7 = Ep[7];
    const float e8 = Ep[8],  e9 = Ep[9],  e10 = Ep[10], e11 = Ep[11];
    const float e12 = Ep[12], e13 = Ep[13], e14 = Ep[14], e15 = Ep[15];

    const f4* __restrict__ x4 = (const f4*)x;
    f4* __restrict__ o4 = (f4*)out + (size_t)t * NN;
    const int base = blockIdx.x * 1024 + threadIdx.x;

    #pragma unroll
    for (int k = 0; k < 4; ++k) {
        const int n = base + k * 256;
        const f4 xv = x4[n];
        f4 o;
        o.x = fmaf(e0,  xv.x, fmaf(e1,  xv.y, fmaf(e2,  xv.z, e3  * xv.w)));
        o.y = fmaf(e4,  xv.x, fmaf(e5,  xv.y, fmaf(e6,  xv.z, e7  * xv.w)));
        o.z = fmaf(e8,  xv.x, fmaf(e9,  xv.y, fmaf(e10, xv.z, e11 * xv.w)));
        o.w = fmaf(e12, xv.x, fmaf(e13, xv.y, fmaf(e14, xv.z, e15 * xv.w)));
        o4[n] = o;   // plain store (reverted from nontemporal)
    }
}

// ---------------------------------------------------------------------------
extern "C" void kernel_launch(void* const* d_in, const int* in_sizes, int n_in,
                              void* d_out, int out_size, void* d_ws, size_t ws_size,
                              hipStream_t stream) {
    const float* x  = (const float*)d_in[0];
    const float* t  = (const float*)d_in[1];
    const float* M0 = (const float*)d_in[2];
    const float* W1 = (const float*)d_in[3];
    const float* b1 = (const float*)d_in[4];
    const float* W2 = (const float*)d_in[5];
    const float* b2 = (const float*)d_in[6];
    const float* W3 = (const float*)d_in[7];
    const float* b3 = (const float*)d_in[8];
    float* out = (float*)d_out;

    float* A_t  = (float*)d_ws;           // 16*TT floats (transposed)
    float* Asum = A_t  + 16 * TT;         // 16*TT floats (t-major)
    float* E    = Asum + 16 * TT;         // 16*TT floats (t-major)

    mlp_kernel<<<TT / TPB, HH, 0, stream>>>(t, M0, W1, b1, W2, b2, W3, b3, A_t);
    scan_expm_kernel<<<1, 1024, 0, stream>>>(A_t, Asum, E);
    apply_kernel<<<dim3(NN / 1024, TT), 256, 0, stream>>>(E, x, out);
}